// Round 1
// baseline (372.997 us; speedup 1.0000x reference)
//
#include <hip/hip_runtime.h>
#include <math.h>

// Problem shape (fixed by setup_inputs)
constexpr int Bn = 8, Dn = 64, Hn = 256, Wn = 512;
constexpr int HW   = Hn * Wn;        // 131072
constexpr int NPIX = Bn * HW;        // 1048576
constexpr int TPB  = 256;
constexpr int PPT  = 4;              // pixels per thread (float4)
constexpr int NBLK = NPIX / (TPB * PPT); // 1024

// entropy(p) = log(sum_d exp(sim_d)) - (sum_d T_d * sim_d) / (sum_d T_d)
// with T_d = exp(-|gt - 2d|). The Laplace 1/(2*DIVERSITY) factor cancels.
__global__ __launch_bounds__(TPB) void sce_main(const float* __restrict__ sim,
                                                const float* __restrict__ gt,
                                                float* __restrict__ acc) {
    const int tid = blockIdx.x * TPB + threadIdx.x;
    const int p0  = tid * PPT;               // first pixel handled by this thread
    const int b   = p0 / HW;
    const int rem = p0 - b * HW;             // contiguous within a batch image
    const float4* simv = reinterpret_cast<const float4*>(sim + (size_t)b * Dn * HW + rem);
    const int dstride = HW / 4;              // float4 stride between d planes

    const float4 g4 = *reinterpret_cast<const float4*>(gt + p0);
    float gg[4] = {g4.x, g4.y, g4.z, g4.w};

    float s[4]  = {0.f, 0.f, 0.f, 0.f};      // sum exp(sim)
    float S1[4] = {0.f, 0.f, 0.f, 0.f};      // sum T
    float S2[4] = {0.f, 0.f, 0.f, 0.f};      // sum T * sim

#pragma unroll 8
    for (int d = 0; d < Dn; ++d) {
        float4 v4 = simv[(size_t)d * dstride];   // coalesced: wave reads 1KiB contiguous
        float v[4] = {v4.x, v4.y, v4.z, v4.w};
        const float dd = 2.0f * (float)d;        // DISPARITY_STEP * d
#pragma unroll
        for (int i = 0; i < 4; ++i) {
            s[i] += __expf(v[i]);
            float t = __expf(-fabsf(gg[i] - dd));
            S1[i] += t;
            S2[i] = fmaf(t, v[i], S2[i]);
        }
    }

    float lsum = 0.0f, lcnt = 0.0f;
#pragma unroll
    for (int i = 0; i < 4; ++i) {
        if (isfinite(gg[i])) {                   // unknown gt = inf -> skip
            lsum += logf(s[i]) - S2[i] / S1[i];
            lcnt += 1.0f;
        }
    }

    // wave (64-lane) shuffle reduction
#pragma unroll
    for (int off = 32; off > 0; off >>= 1) {
        lsum += __shfl_down(lsum, off, 64);
        lcnt += __shfl_down(lcnt, off, 64);
    }

    __shared__ float ssum[TPB / 64], scnt[TPB / 64];
    const int lane = threadIdx.x & 63;
    const int wave = threadIdx.x >> 6;
    if (lane == 0) { ssum[wave] = lsum; scnt[wave] = lcnt; }
    __syncthreads();
    if (threadIdx.x == 0) {
        float bs = 0.f, bc = 0.f;
#pragma unroll
        for (int w = 0; w < TPB / 64; ++w) { bs += ssum[w]; bc += scnt[w]; }
        atomicAdd(&acc[0], bs);
        atomicAdd(&acc[1], bc);
    }
}

__global__ void sce_final(const float* __restrict__ acc, float* __restrict__ out) {
    out[0] = acc[0] / acc[1];
}

extern "C" void kernel_launch(void* const* d_in, const int* in_sizes, int n_in,
                              void* d_out, int out_size, void* d_ws, size_t ws_size,
                              hipStream_t stream) {
    const float* sim = (const float*)d_in[0];
    const float* gt  = (const float*)d_in[1];
    float* acc = (float*)d_ws;                       // [sum, count]
    hipMemsetAsync(acc, 0, 2 * sizeof(float), stream);  // ws is re-poisoned 0xAA each call
    sce_main<<<NBLK, TPB, 0, stream>>>(sim, gt, acc);
    sce_final<<<1, 1, 0, stream>>>(acc, (float*)d_out);
}